// Round 3
// baseline (29.060 us; speedup 1.0000x reference)
//
#include <hip/hip_runtime.h>

// Depthwise causal FIR conv1d.
// x: (B, L, H, D) fp32, filters: (H, D, K) fp32, y: (B, L, H, D) fp32
// y[b,l,c] = sum_k filt[c,k] * x[b, l-6+k, c]   (zero-padded for l-6+k < 0)
// C = H*D = 1024 contiguous innermost -> vectorize channels as 4-wide vectors.
// LCHUNK=16: 1024 blocks -> 4 waves/SIMD (TLP for latency hiding).
// nt-store for y (no reuse of output).

typedef float f32x4 __attribute__((ext_vector_type(4)));

constexpr int B_ = 4;
constexpr int L_ = 4096;
constexpr int H_ = 16;
constexpr int D_ = 64;
constexpr int K_ = 7;
constexpr int C_ = H_ * D_;      // 1024
constexpr int C4_ = C_ / 4;      // 256 channel-groups of 4
constexpr int LCHUNK = 16;       // L rows per block
constexpr int NCHUNK = L_ / LCHUNK;  // 256

__global__ __launch_bounds__(256)
void dwfir_kernel(const float* __restrict__ x,
                  const float* __restrict__ filt,
                  float* __restrict__ y) {
    const int c4 = threadIdx.x;              // 0..255 -> channels 4*c4 .. 4*c4+3
    const int chunk = blockIdx.x;            // 0 .. B_*NCHUNK-1
    const int b  = chunk / NCHUNK;
    const int l0 = (chunk % NCHUNK) * LCHUNK;

    // ---- filters: 28 consecutive floats per thread (channel-major [c][k]),
    //      112 B per thread, 16B-aligned -> 7 vec4 loads, static unpack.
    const f32x4* fv = reinterpret_cast<const f32x4*>(filt) + c4 * 7;
    float ff[28];
    #pragma unroll
    for (int i = 0; i < 7; ++i) {
        f32x4 t = fv[i];
        ff[4 * i + 0] = t.x;
        ff[4 * i + 1] = t.y;
        ff[4 * i + 2] = t.z;
        ff[4 * i + 3] = t.w;
    }
    // ff[ch*7 + k] = filt[4*c4 + ch][k]

    const f32x4* xv = reinterpret_cast<const f32x4*>(x);
    f32x4*       yv = reinterpret_cast<f32x4*>(y);

    // ---- preload sliding window: w[j] = x[b, l0-6+j, :] for j=0..5
    f32x4 w[7];
    #pragma unroll
    for (int j = 0; j < 6; ++j) {
        const int l = l0 - 6 + j;
        if (l >= 0) {
            w[j] = xv[(size_t)(b * L_ + l) * C4_ + c4];
        } else {
            w[j] = (f32x4)(0.f);
        }
    }

    // ---- main loop; all indices static under full unroll
    #pragma unroll
    for (int i = 0; i < LCHUNK; ++i) {
        const int l = l0 + i;
        const size_t off = (size_t)(b * L_ + l) * C4_ + c4;
        w[6] = xv[off];

        f32x4 acc;
        acc.x = ff[0]  * w[0].x;
        acc.y = ff[7]  * w[0].y;
        acc.z = ff[14] * w[0].z;
        acc.w = ff[21] * w[0].w;
        #pragma unroll
        for (int k = 1; k < 7; ++k) {
            acc.x = fmaf(ff[k],      w[k].x, acc.x);
            acc.y = fmaf(ff[7 + k],  w[k].y, acc.y);
            acc.z = fmaf(ff[14 + k], w[k].z, acc.z);
            acc.w = fmaf(ff[21 + k], w[k].w, acc.w);
        }
        __builtin_nontemporal_store(acc, &yv[off]);

        #pragma unroll
        for (int j = 0; j < 6; ++j) w[j] = w[j + 1];
    }
}

extern "C" void kernel_launch(void* const* d_in, const int* in_sizes, int n_in,
                              void* d_out, int out_size, void* d_ws, size_t ws_size,
                              hipStream_t stream) {
    const float* x    = (const float*)d_in[0];
    const float* filt = (const float*)d_in[1];
    float*       y    = (float*)d_out;

    dim3 grid(B_ * NCHUNK);   // 1024 blocks
    dim3 block(256);
    dwfir_kernel<<<grid, block, 0, stream>>>(x, filt, y);
}